// Round 5
// baseline (175.253 us; speedup 1.0000x reference)
//
#include <hip/hip_runtime.h>
#include <stdint.h>

#define N_ROWS 8192
#define FEAT   256
#define XBLK   64                   // row blocks of 128 rows (4 waves x 32)
#define YSPLIT 16
#define CPB    (N_ROWS / YSPLIT)    // 512 cols per kmain block
#define CT     64                   // cols staged per chunk
#define NBLK   (XBLK * YSPLIT)      // 1024 kmain blocks

typedef float f32x4 __attribute__((ext_vector_type(4)));
typedef const uint8_t __attribute__((address_space(1))) gl_u8;
typedef uint8_t __attribute__((address_space(3))) lds_u8;

// ---- Kernel 1: normalize rows -> fp8 e4m3 (x16); pos dot; zero partial ---
__global__ void knorm(const float* __restrict__ feat,
                      uint32_t* __restrict__ f8,
                      float* __restrict__ pos,
                      float* __restrict__ partial,
                      unsigned int* __restrict__ cnt) {
    __shared__ float ex[4][FEAT];
    int wave = threadIdx.x >> 6;
    int lane = threadIdx.x & 63;
    int row  = blockIdx.x * 4 + wave;
    if (blockIdx.x == 0 && threadIdx.x == 0) *cnt = 0;
    float4 v = ((const float4*)(feat + row * FEAT))[lane];
    float ss = v.x*v.x + v.y*v.y + v.z*v.z + v.w*v.w;
    #pragma unroll
    for (int off = 1; off < 64; off <<= 1) ss += __shfl_xor(ss, off);
    float inv = 1.0f / fmaxf(sqrtf(ss), 1e-12f);
    float4 o; o.x = v.x*inv; o.y = v.y*inv; o.z = v.z*inv; o.w = v.w*inv;
    const float s = 16.0f;   // entries -> e4m3 sweet range
    uint32_t p = __builtin_amdgcn_cvt_pk_fp8_f32(o.x*s, o.y*s, 0, false);
    p = __builtin_amdgcn_cvt_pk_fp8_f32(o.z*s, o.w*s, p, true);
    f8[row * (FEAT/4) + lane] = p;
    ((float4*)ex[wave])[lane] = o;
    if (lane == 0) partial[row] = 0.f;      // zero the atomic accumulator
    __syncthreads();
    float4 q = ((float4*)ex[wave ^ 1])[lane];
    float d = o.x*q.x + o.y*q.y + o.z*q.z + o.w*q.w;
    #pragma unroll
    for (int off = 1; off < 64; off <<= 1) d += __shfl_xor(d, off);
    if (lane == 0) pos[row] = d;
}

// ---- Kernel 2: fp8 f@f^T + fused exp-sum + decoupled last-block finale ---
// grid (XBLK, YSPLIT), 256 threads (4 waves x 32 rows = 128 rows/block).
// LDS: CT cols x 256B, XOR-swizzled (o ^= (col&7)<<4) -> 2-way banks max,
// lane-contiguous for global_load_lds width=16.
__global__ __launch_bounds__(256, 5)
void kmain(const uint8_t* __restrict__ f8,
           const float* __restrict__ pos,
           float* __restrict__ partial,
           unsigned int* __restrict__ cnt,
           float* __restrict__ out) {
    __shared__ uint8_t Bs[CT * 256];        // 16 KB, no pad (swizzled)
    __shared__ float red[4];
    __shared__ unsigned int flag;
    const int t    = threadIdx.x;
    const int lane = t & 63;
    const int wave = t >> 6;          // 0..3
    const int quad = lane >> 4;
    const int l15  = lane & 15;
    const int rw    = blockIdx.x * 128 + wave * 32;
    const int cbase = blockIdx.y * CPB;
    const float Kc = 20.60992915555662f;   // log2(e)/0.07
    const float Ks = Kc / 256.0f;          // acc carries 256*s (x16 * x16)

    // A frags: 32 rows x K=256 fp8 in registers (32 VGPRs)
    long af[2][8];
    #pragma unroll
    for (int rg = 0; rg < 2; ++rg)
        #pragma unroll
        for (int ks = 0; ks < 8; ++ks)
            af[rg][ks] = *(const long*)(f8 + (rw + rg*16 + l15) * FEAT + ks*32 + quad*8);

    float lsum[2][4] = {};

    for (int ct = 0; ct < CPB / CT; ++ct) {
        __syncthreads();
        const int c0 = cbase + ct * CT;
        // stage CT cols x 256 B via async DMA: 4 issues/wave x 1 KB
        #pragma unroll
        for (int j = 0; j < 4; ++j) {
            int Lb  = (wave * 4 + j) * 1024;
            int L   = Lb + lane * 16;
            int col = L >> 8;
            int o   = (L & 255) ^ ((col & 7) << 4);     // source-side swizzle
            __builtin_amdgcn_global_load_lds(
                (gl_u8*)(f8 + (size_t)(c0 + col) * FEAT + o),
                (lds_u8*)(Bs + Lb), 16, 0, 0);
        }
        __syncthreads();

        #pragma unroll
        for (int g = 0; g < 4; ++g) {
            const int col  = g * 16 + l15;
            const int base = col * 256;
            const int sw   = (col & 7) << 4;
            f32x4 acc[2] = {{0,0,0,0},{0,0,0,0}};
            #pragma unroll
            for (int ks = 0; ks < 8; ++ks) {
                long b = *(const long*)(Bs + base + ((ks*32 + quad*8) ^ sw));
                acc[0] = __builtin_amdgcn_mfma_f32_16x16x32_fp8_fp8(af[0][ks], b, acc[0], 0, 0, 0);
                acc[1] = __builtin_amdgcn_mfma_f32_16x16x32_fp8_fp8(af[1][ks], b, acc[1], 0, 0, 0);
            }
            const int cg = c0 + g * 16;
            #pragma unroll
            for (int rg = 0; rg < 2; ++rg) {
                const bool dg = (cg == rw + rg * 16);   // wave-uniform diag
                #pragma unroll
                for (int r = 0; r < 4; ++r) {
                    float e = __builtin_amdgcn_exp2f(fmaf(acc[rg][r], Ks, -Kc));
                    if (dg && l15 == quad * 4 + r) e = 0.f;   // mask j == i
                    lsum[rg][r] += e;
                }
            }
        }
    }

    // reduce across the 16 col-lanes; accumulate into global per-row sums
    #pragma unroll
    for (int rg = 0; rg < 2; ++rg)
        #pragma unroll
        for (int r = 0; r < 4; ++r) {
            float v = lsum[rg][r];
            v += __shfl_xor(v, 1);
            v += __shfl_xor(v, 2);
            v += __shfl_xor(v, 4);
            v += __shfl_xor(v, 8);
            if (l15 == 0)
                atomicAdd(&partial[rw + rg*16 + quad*4 + r], v);  // 16 adds/addr
        }

    // ---- decoupled completion: last block computes the loss --------------
    __threadfence();
    __syncthreads();
    if (t == 0) {
        unsigned int old = __hip_atomic_fetch_add(cnt, 1u, __ATOMIC_ACQ_REL,
                                                  __HIP_MEMORY_SCOPE_AGENT);
        flag = (old == NBLK - 1) ? 1u : 0u;
    }
    __syncthreads();
    if (flag) {
        const float invT = 14.285714285714286f;
        float acc = 0.f;
        #pragma unroll
        for (int k = 0; k < 32; ++k) {
            int row = t + k * 256;
            float L = __hip_atomic_load(&partial[row], __ATOMIC_RELAXED,
                                        __HIP_MEMORY_SCOPE_AGENT);
            float p = pos[row];
            acc += invT * (1.0f - p)
                 + 0.6931471805599453f * __builtin_amdgcn_logf(L);
        }
        #pragma unroll
        for (int off = 1; off < 64; off <<= 1) acc += __shfl_xor(acc, off);
        if (lane == 0) red[wave] = acc;
        __syncthreads();
        if (t == 0)
            out[0] = (red[0] + red[1] + red[2] + red[3]) * (1.0f / 8192.0f);
    }
}

extern "C" void kernel_launch(void* const* d_in, const int* in_sizes, int n_in,
                              void* d_out, int out_size, void* d_ws, size_t ws_size,
                              hipStream_t stream) {
    const float* feat = (const float*)d_in[0];
    float* out = (float*)d_out;
    char* ws = (char*)d_ws;
    uint32_t*     f8      = (uint32_t*)ws;                          // 2 MB fp8
    float*        partial = (float*)(ws + (2u << 20));              // 32 KB
    float*        pos     = (float*)(ws + (2u << 20) + (1u << 15)); // 32 KB
    unsigned int* cnt     = (unsigned int*)(ws + (2u << 20) + (2u << 15));

    knorm<<<N_ROWS / 4, 256, 0, stream>>>(feat, f8, pos, partial, cnt);
    kmain<<<dim3(XBLK, YSPLIT), 256, 0, stream>>>((const uint8_t*)f8, pos,
                                                  partial, cnt, out);
}